// Round 16
// baseline (173.518 us; speedup 1.0000x reference)
//
#include <hip/hip_runtime.h>

// LocallyLowRank: N=4, A=16, H=W=384, 8x8 blocks stride 4 -> NB=95.
// out[p,:] = x[p,:] * S_p / w_p,  S_p = sum_{b covering p} Phi_b,
// Phi_b = V max(1-2/sigma,0)/1 V^T from G = m_b^T m_b (one-sided Jacobi).
//
// R22: Phi stored in BF16 (packed 2/dword). phiG 37->18.5 MB (L2-resident),
// out2's Phi-gather bytes halve (147->74 MB traffic), llr_phi writes halve.
// Pack: plain-LDS-loaded floats -> inline-asm cvtpk (Gram-proven direction);
// unpack: bit-ops + builtin adds. S layout in LDS + compute unchanged.
// Accuracy: Phi rel err 2^-9 -> out absmax +~0.01-0.02 over the 0.041
// output-quantization floor; threshold 0.084.
// HARD RULES: (a) never feed ds_swizzle results into INLINE-ASM consumers
// (builtin consumers safe -- R7/R8/R18); (b) never feed MFMA results into
// inline-asm consumers (plain store only); (c) NSWEEP_=4 minimum (R14);
// (d) out2 stages S gather first, x loads in the barrier shadow (R17);
// (e) no occupancy-for-ILP trades at high VALUBusy (R20).

typedef __attribute__((ext_vector_type(2))) float v2f;
typedef __attribute__((ext_vector_type(4))) float f32x4;
typedef __attribute__((ext_vector_type(8))) short s16x8;
typedef union { float4 f4; v2f v2[2]; } f4v2;

#define N_      4
#define A_      16
#define H_      384
#define W_      384
#define PLANE_  (H_*W_)       // 147456
#define NB_     95
#define NBB_    (NB_*NB_)     // 9025
#define NMAT_   (N_*NBB_)     // 36100
#define NWAVE_  ((NMAT_ + 3) / 4)   // 9025
#define NSWEEP_ 4
#define PHI_BYTES_ ((size_t)NMAT_ * 256 * 4)   // ws requirement (uses half)

// ---- packed fp32 ops, forced (VOP3P) -- used ONLY where inputs are
// compiler-visible plain values (Phase 2, out2) ------------------------------
__device__ __forceinline__ v2f pk_fma(v2f a, v2f b, v2f c) {
    v2f d; asm("v_pk_fma_f32 %0, %1, %2, %3" : "=v"(d) : "v"(a), "v"(b), "v"(c));
    return d;
}
__device__ __forceinline__ v2f pk_mul(v2f a, v2f b) {
    v2f d; asm("v_pk_mul_f32 %0, %1, %2" : "=v"(d) : "v"(a), "v"(b));
    return d;
}

// ---- bf16 pack/unpack helpers ----------------------------------------------
__device__ __forceinline__ unsigned cvtpk_bf16(float a, float b) {
    unsigned d;   // d[15:0]=bf16(a), d[31:16]=bf16(b), RNE
    asm("v_cvt_pk_bf16_f32 %0, %1, %2" : "=v"(d) : "v"(a), "v"(b));
    return d;
}
__device__ __forceinline__ float asf_(unsigned u) {
    union { unsigned u; float f; } x; x.u = u; return x.f;
}
__device__ __forceinline__ float bflo_(unsigned u) { return asf_(u << 16); }
__device__ __forceinline__ float bfhi_(unsigned u) { return asf_(u & 0xFFFF0000u); }
typedef union { s16x8 s8; unsigned u[4]; } frag8;

// split 8 fp32 (two float4) into bf16 hi frag + bf16 lo frag (residual)
__device__ __forceinline__ void split8(const float4 A, const float4 B,
                                       frag8& hi, frag8& lo) {
    hi.u[0] = cvtpk_bf16(A.x, A.y);
    hi.u[1] = cvtpk_bf16(A.z, A.w);
    hi.u[2] = cvtpk_bf16(B.x, B.y);
    hi.u[3] = cvtpk_bf16(B.z, B.w);
    const float l0 = A.x - bflo_(hi.u[0]);
    const float l1 = A.y - bfhi_(hi.u[0]);
    const float l2 = A.z - bflo_(hi.u[1]);
    const float l3 = A.w - bfhi_(hi.u[1]);
    const float l4 = B.x - bflo_(hi.u[2]);
    const float l5 = B.y - bfhi_(hi.u[2]);
    const float l6 = B.z - bflo_(hi.u[3]);
    const float l7 = B.w - bfhi_(hi.u[3]);
    lo.u[0] = cvtpk_bf16(l0, l1);
    lo.u[1] = cvtpk_bf16(l2, l3);
    lo.u[2] = cvtpk_bf16(l4, l5);
    lo.u[3] = cvtpk_bf16(l6, l7);
}

// ---- single DPP16 primitive ------------------------------------------------
template<int CTRL>
__device__ __forceinline__ float dpp16(float v) {
    union { float f; int i; } u; u.f = v;
    u.i = __builtin_amdgcn_mov_dpp(u.i, CTRL, 0xF, 0xF, true);
    return u.f;
}

#define QP1_ 0xB1   // quad_perm [1,0,3,2] = xor 1
#define QP2_ 0x4E   // quad_perm [2,3,0,1] = xor 2
#define QP3_ 0x1B   // quad_perm [3,2,1,0] = xor 3
#define HM_  0x141  // row_half_mirror = xor 7
#define FM_  0x140  // row_mirror      = xor 15
#define R8_  0x128  // row_ror:8       = xor 8

// ---- 16-lane xor exchange: 1-DPP masks on VALU; 2-DPP masks via single
// ds_swizzle on the LDS pipe. Consumers in jacobi_round are builtins ->
// compiler inserts lgkmcnt (R7/R8/R18-proven-safe combination). -------------
template<int M>
__device__ __forceinline__ float lane_xor16(float v) {
    if constexpr (M == 1)       return dpp16<QP1_>(v);
    else if constexpr (M == 2)  return dpp16<QP2_>(v);
    else if constexpr (M == 3)  return dpp16<QP3_>(v);
    else if constexpr (M == 7)  return dpp16<HM_>(v);
    else if constexpr (M == 8)  return dpp16<R8_>(v);
    else if constexpr (M == 15) return dpp16<FM_>(v);
    else {
        // BitMode: new_lane = (lane & 0x1F) ^ M. One LDS-pipe inst vs
        // two chained VALU DPPs.
        union { float f; int i; } u; u.f = v;
        u.i = __builtin_amdgcn_ds_swizzle(u.i, (M << 10) | 0x1F);
        return u.f;
    }
}

// One Jacobi rotation round on packed column state w[8] (=16 floats).
// R15 zeta-form rotation math. ALL ops compiler-visible (no inline asm):
// safe with ds_swizzle exchanges (R18-proven).
template<int M>
__device__ __forceinline__ void jacobi_round(v2f w[8], float& nrm, const int j) {
    v2f pw[8];
    #pragma unroll
    for (int i = 0; i < 8; ++i) {
        pw[i][0] = lane_xor16<M>(w[i][0]);
        pw[i][1] = lane_xor16<M>(w[i][1]);
    }
    const float pn = lane_xor16<M>(nrm);

    v2f d0 = w[0]*pw[0], d1 = w[1]*pw[1];
    #pragma unroll
    for (int i = 2; i < 8; i += 2) {
        d0 = __builtin_elementwise_fma(w[i],   pw[i],   d0);
        d1 = __builtin_elementwise_fma(w[i+1], pw[i+1], d1);
    }
    const v2f ds = d0 + d1;
    const float gam = ds[0] + ds[1];

    const bool  low = ((j ^ M) > j);        // canonical order -> identical c,s
    const float na  = low ? nrm : pn;
    const float nb  = low ? pn  : nrm;

    const float thr = 1e-12f * (na + nb);
    const bool  rot = fabsf(gam) > thr;
    const float gs  = rot ? gam : 1.f;
    const float zeta = (nb - na) * (0.5f * __builtin_amdgcn_rcpf(gs));
    const float rt   = __builtin_amdgcn_rcpf(
                           fabsf(zeta) +
                           __builtin_amdgcn_sqrtf(__builtin_fmaf(zeta, zeta, 1.f)));
    float t  = copysignf(rt, zeta);
    float c  = __builtin_amdgcn_rsqf(__builtin_fmaf(t, t, 1.f));
    float sv = c * t;
    if (!rot) { c = 1.f; sv = 0.f; t = 0.f; }

    const float ss = low ? -sv : sv;
    const v2f c2 = {c, c}, sp = {ss, ss};
    #pragma unroll
    for (int i = 0; i < 8; ++i)
        w[i] = __builtin_elementwise_fma(c2, w[i], sp*pw[i]);

    // Rutishauser: norm update at the zeroing rotation.
    nrm = __builtin_fmaf(low ? -t : t, gam, nrm);
}

// Shared phases 1-4: Gram (MFMA) + Jacobi + Phi (MFMA; Phi left in Gl).
// One wave, 4 matrices, 16 lanes/matrix. No block barriers.
__device__ __forceinline__ void gram_jacobi_phi(
        const float* __restrict__ x, const int wid, const int warp,
        const int lane, float Gl[4][4][320]) {
    const int g   = lane >> 4;
    const int j   = lane & 15;
    const int kq4 = g * 4;

    // -------- Phase 1: Gram via MFMA (no LDS, no barriers) ------------------
    // lane = (channel j, k-block g): loads channel j, block rows g and g+4,
    // all 8 cols -> A-frag == B-frag of G = M^T M.
    // MFMA results consumed ONLY by plain stores (hard rule b).
    #pragma unroll
    for (int s = 0; s < 4; ++s) {
        const int id  = wid * 4 + s;
        const int n   = id / NBB_;
        const int rem = id % NBB_;
        const int bi  = rem / NB_;
        const int bj  = rem % NB_;
        const float* bp = x + (size_t)n * (A_ * PLANE_) + (size_t)j * PLANE_
                            + (bi*4 + g) * W_ + bj*4;

        const float4 va = *(const float4*)(bp);
        const float4 vb = *(const float4*)(bp + 4);
        const float4 vc = *(const float4*)(bp + 4*W_);
        const float4 vd = *(const float4*)(bp + 4*W_ + 4);

        frag8 hi0, lo0, hi1, lo1;
        split8(va, vb, hi0, lo0);
        split8(vc, vd, hi1, lo1);

        f32x4 C = {0.f, 0.f, 0.f, 0.f};
        C = __builtin_amdgcn_mfma_f32_16x16x32_bf16(lo0.s8, hi0.s8, C, 0, 0, 0);
        C = __builtin_amdgcn_mfma_f32_16x16x32_bf16(hi0.s8, lo0.s8, C, 0, 0, 0);
        C = __builtin_amdgcn_mfma_f32_16x16x32_bf16(hi0.s8, hi0.s8, C, 0, 0, 0);
        C = __builtin_amdgcn_mfma_f32_16x16x32_bf16(lo1.s8, hi1.s8, C, 0, 0, 0);
        C = __builtin_amdgcn_mfma_f32_16x16x32_bf16(hi1.s8, lo1.s8, C, 0, 0, 0);
        C = __builtin_amdgcn_mfma_f32_16x16x32_bf16(hi1.s8, hi1.s8, C, 0, 0, 0);

        // C lane layout: col=lane&15 (=j), row=4*(lane>>4)+r (=kq4+r):
        // exactly the per-lane Gram output layout.
        *(float4*)&Gl[warp][s][j*20 + kq4] = make_float4(C[0], C[1], C[2], C[3]);
    }
    __builtin_amdgcn_wave_barrier();

    // -------- Phase 2: my column into registers -----------------------------
    v2f w[8];
    {
        f4v2 t0, t1, t2, t3;
        t0.f4 = *(const float4*)&Gl[warp][g][j*20 + 0];
        t1.f4 = *(const float4*)&Gl[warp][g][j*20 + 4];
        t2.f4 = *(const float4*)&Gl[warp][g][j*20 + 8];
        t3.f4 = *(const float4*)&Gl[warp][g][j*20 + 12];
        w[0]=t0.v2[0]; w[1]=t0.v2[1]; w[2]=t1.v2[0]; w[3]=t1.v2[1];
        w[4]=t2.v2[0]; w[5]=t2.v2[1]; w[6]=t3.v2[0]; w[7]=t3.v2[1];
    }
    float nrm;
    {
        v2f d = pk_mul(w[0], w[0]);
        #pragma unroll
        for (int i = 1; i < 8; ++i) d = pk_fma(w[i], w[i], d);
        nrm = d[0] + d[1];
    }

    // -------- Phase 3: one-sided Jacobi (4 sweeps REQUIRED, R14) ------------
    for (int sweep = 0; sweep < NSWEEP_; ++sweep) {
        jacobi_round<1>(w, nrm, j);  jacobi_round<2>(w, nrm, j);
        jacobi_round<3>(w, nrm, j);  jacobi_round<4>(w, nrm, j);
        jacobi_round<5>(w, nrm, j);  jacobi_round<6>(w, nrm, j);
        jacobi_round<7>(w, nrm, j);  jacobi_round<8>(w, nrm, j);
        jacobi_round<9>(w, nrm, j);  jacobi_round<10>(w, nrm, j);
        jacobi_round<11>(w, nrm, j); jacobi_round<12>(w, nrm, j);
        jacobi_round<13>(w, nrm, j); jacobi_round<14>(w, nrm, j);
        jacobi_round<15>(w, nrm, j);
    }
    {   // exact norm (drift removal)
        v2f d = pk_mul(w[0], w[0]);
        #pragma unroll
        for (int i = 1; i < 8; ++i) d = pk_fma(w[i], w[i], d);
        nrm = d[0] + d[1];
    }
    float rho = 0.f;                         // max(1-2/sigma,0)/lam^2
    if (nrm > 16.f) {
        const float lam = __builtin_amdgcn_sqrtf(nrm);
        rho = (1.f - 2.f * __builtin_amdgcn_rsqf(lam)) * __builtin_amdgcn_rcpf(nrm);
    }

    __builtin_amdgcn_wave_barrier();
    *(float4*)&Gl[warp][g][j*20 + 0]  = make_float4(w[0][0], w[0][1], w[1][0], w[1][1]);
    *(float4*)&Gl[warp][g][j*20 + 4]  = make_float4(w[2][0], w[2][1], w[3][0], w[3][1]);
    *(float4*)&Gl[warp][g][j*20 + 8]  = make_float4(w[4][0], w[4][1], w[5][0], w[5][1]);
    *(float4*)&Gl[warp][g][j*20 + 12] = make_float4(w[6][0], w[6][1], w[7][0], w[7][1]);
    Gl[warp][g][j*20 + 16] = rho;
    __builtin_amdgcn_wave_barrier();

    // -------- Phase 4 (MFMA): Phi_s = (rho (.) W) W^T, K=16 padded to 32 ----
    // lane&15 = Phi row i (A) = Phi col j (B): the same LDS reads build both
    // fragments. kgroups (lane>>4) 0,1 carry k=0..15; 2,3 supply zeros.
    // bf16 hi/lo on both operands, drop lo*lo. MFMA dest -> plain stores.
    {
        const int kg = lane >> 4;
        const int mn = lane & 15;
        f32x4 PhiC[4];
        #pragma unroll
        for (int s = 0; s < 4; ++s) {
            frag8 Ahi, Alo, Bhi, Blo;
            if (kg < 2) {
                float av[8], bv[8];
                #pragma unroll
                for (int e = 0; e < 8; ++e) {
                    const int k = kg*8 + e;
                    const float wv = Gl[warp][s][k*20 + mn];
                    const float rh = Gl[warp][s][k*20 + 16];
                    bv[e] = wv;
                    av[e] = wv * rh;
                }
                split8(make_float4(av[0],av[1],av[2],av[3]),
                       make_float4(av[4],av[5],av[6],av[7]), Ahi, Alo);
                split8(make_float4(bv[0],bv[1],bv[2],bv[3]),
                       make_float4(bv[4],bv[5],bv[6],bv[7]), Bhi, Blo);
            } else {
                Ahi.u[0]=0u; Ahi.u[1]=0u; Ahi.u[2]=0u; Ahi.u[3]=0u;
                Alo = Ahi; Bhi = Ahi; Blo = Ahi;
            }
            f32x4 C = {0.f, 0.f, 0.f, 0.f};
            C = __builtin_amdgcn_mfma_f32_16x16x32_bf16(Alo.s8, Bhi.s8, C, 0, 0, 0);
            C = __builtin_amdgcn_mfma_f32_16x16x32_bf16(Ahi.s8, Blo.s8, C, 0, 0, 0);
            C = __builtin_amdgcn_mfma_f32_16x16x32_bf16(Ahi.s8, Bhi.s8, C, 0, 0, 0);
            PhiC[s] = C;
        }
        __builtin_amdgcn_wave_barrier();      // all W/rho reads done -> overwrite
        #pragma unroll
        for (int s = 0; s < 4; ++s) {
            #pragma unroll
            for (int r2 = 0; r2 < 4; ++r2)
                Gl[warp][s][(4*kg + r2)*20 + mn] = PhiC[s][r2];
        }
        __builtin_amdgcn_wave_barrier();
    }
}

// =================== K1: Phi per block -> global (bf16-packed) ==============
__global__ __launch_bounds__(256, 8)
void llr_phi(const float* __restrict__ x, unsigned* __restrict__ phiG) {
    __shared__ __align__(16) float Gl[4][4][320];   // 20480 B -> 8 blocks/CU
    const int warp = threadIdx.x >> 6;
    const int lane = threadIdx.x & 63;

    // bijective XCD-chunked swizzle: nwg=2257, q=282, r=1.
    const int xcd = blockIdx.x & 7, idx = blockIdx.x >> 3;
    const int wg  = (xcd == 0 ? idx : 283 + (xcd - 1) * 282 + idx);
    const int wid = wg * 4 + warp;
    if (wid >= NWAVE_) return;

    gram_jacobi_phi(x, wid, warp, lane, Gl);

    // Phi symmetric -> column j IS row j. Pack row j (16 fp32, plain LDS
    // loads) into 8 bf16x2 dwords via cvtpk (Gram-proven direction), store
    // 32B contiguous per lane.
    const int g = lane >> 4, j = lane & 15;
    unsigned* pb = phiG + (size_t)(wid*4 + g) * 128 + j * 8;
    const float4 p0 = *(const float4*)&Gl[warp][g][j*20 + 0];
    const float4 p1 = *(const float4*)&Gl[warp][g][j*20 + 4];
    const float4 p2 = *(const float4*)&Gl[warp][g][j*20 + 8];
    const float4 p3 = *(const float4*)&Gl[warp][g][j*20 + 12];
    uint4 q0, q1;
    q0.x = cvtpk_bf16(p0.x, p0.y);  q0.y = cvtpk_bf16(p0.z, p0.w);
    q0.z = cvtpk_bf16(p1.x, p1.y);  q0.w = cvtpk_bf16(p1.z, p1.w);
    q1.x = cvtpk_bf16(p2.x, p2.y);  q1.y = cvtpk_bf16(p2.z, p2.w);
    q1.z = cvtpk_bf16(p3.x, p3.y);  q1.w = cvtpk_bf16(p3.z, p3.w);
    *(uint4*)&pb[0] = q0;
    *(uint4*)&pb[4] = q1;
}

// =================== K2: out = x * (sum Phi)/w, tiled 8x32 px ===============
__global__ __launch_bounds__(256, 8)
void llr_out2(const float* __restrict__ x, const unsigned* __restrict__ phiG,
              float* __restrict__ out) {
    __shared__ __align__(16) float Sl[16][260];   // stride 260: conflict-free reads

    // bijective XCD-chunked swizzle: nwg=2304 (divisible by 8), q=288.
    const int b  = (blockIdx.x & 7) * 288 + (blockIdx.x >> 3);
    const int n  = b / 576;
    const int tt = b % 576;
    const int tr = tt / 12, tc = tt % 12;
    const int r0 = tr*8, c0 = tc*32;
    const int cr0 = tr*2, cc0 = tc*8;   // global cell coords of tile origin

    const int r = threadIdx.x >> 5;          // 0..7 (wave = 2 rows, same cell-row)
    const int c = threadIdx.x & 31;          // 0..31 -> coalesced
    const int lcc = ((r >> 2) << 3) + (c >> 2);
    const size_t sb = (size_t)n * (A_*PLANE_) + (size_t)(r0 + r) * W_ + (c0 + c);

    // -------- stage S FIRST (critical-path gather issued first, rule d): ----
    // bf16-packed Phi: clamped 4-load (uint2 = 4 bf16 values) sum * 0.25.
    {
        const int lc  = threadIdx.x >> 4;        // local cell 0..15
        const int fo  = (threadIdx.x & 15) * 4;  // float offset 0..60
        const int fo2 = (threadIdx.x & 15) * 2;  // dword offset 0..30
        const int ci = cr0 + (lc >> 3);
        const int cj = cc0 + (lc & 7);
        const int bi0 = max(ci - 1, 0), bi1 = min(ci, NB_ - 1);
        const int bj0 = max(cj - 1, 0), bj1 = min(cj, NB_ - 1);
        const size_t r00 = ((size_t)(n*NBB_ + bi0*NB_ + bj0))*128;
        const size_t r01 = ((size_t)(n*NBB_ + bi0*NB_ + bj1))*128;
        const size_t r10 = ((size_t)(n*NBB_ + bi1*NB_ + bj0))*128;
        const size_t r11 = ((size_t)(n*NBB_ + bi1*NB_ + bj1))*128;
        #pragma unroll
        for (int it = 0; it < 4; ++it) {
            const int doff = fo2 + it*32;
            const uint2 a  = *(const uint2*)&phiG[r00 + doff];
            const uint2 bq = *(const uint2*)&phiG[r01 + doff];
            const uint2 cq = *(const uint2*)&phiG[r10 + doff];
            const uint2 d  = *(const uint2*)&phiG[r11 + doff];
            float4 s;
            s.x = (bflo_(a.x) + bflo_(bq.x) + bflo_(cq.x) + bflo_(d.x)) * 0.25f;
            s.y = (bfhi_(a.x) + bfhi_(bq.x) + bfhi_(cq.x) + bfhi_(d.x)) * 0.25f;
            s.z = (bflo_(a.y) + bflo_(bq.y) + bflo_(cq.y) + bflo_(d.y)) * 0.25f;
            s.w = (bfhi_(a.y) + bfhi_(bq.y) + bfhi_(cq.y) + bfhi_(d.y)) * 0.25f;
            *(float4*)&Sl[lc][fo + it*64] = s;
        }
    }

    // -------- x loads: issued AFTER the gather (already in flight), BEFORE
    // the barrier -- their latency hides under the barrier wait. ------------
    float xk[16];
    #pragma unroll
    for (int k = 0; k < 16; ++k) xk[k] = x[sb + (size_t)k * PLANE_];

    __syncthreads();

    // -------- compute: thread = 1 pixel, all 16 channels --------------------
    v2f acc[8];
    #pragma unroll
    for (int i = 0; i < 8; ++i) acc[i] = (v2f){0.f, 0.f};
    #pragma unroll
    for (int k = 0; k < 16; ++k) {
        const v2f xv = {xk[k], xk[k]};
        f4v2 s0, s1, s2, s3;
        s0.f4 = *(const float4*)&Sl[lcc][k*16 + 0];
        s1.f4 = *(const float4*)&Sl[lcc][k*16 + 4];
        s2.f4 = *(const float4*)&Sl[lcc][k*16 + 8];
        s3.f4 = *(const float4*)&Sl[lcc][k*16 + 12];
        acc[0] = pk_fma(xv, s0.v2[0], acc[0]);
        acc[1] = pk_fma(xv, s0.v2[1], acc[1]);
        acc[2] = pk_fma(xv, s1.v2[0], acc[2]);
        acc[3] = pk_fma(xv, s1.v2[1], acc[3]);
        acc[4] = pk_fma(xv, s2.v2[0], acc[4]);
        acc[5] = pk_fma(xv, s2.v2[1], acc[5]);
        acc[6] = pk_fma(xv, s3.v2[0], acc[6]);
        acc[7] = pk_fma(xv, s3.v2[1], acc[7]);
    }
    #pragma unroll
    for (int i = 0; i < 8; ++i) {
        out[sb + (size_t)(2*i)     * PLANE_] = acc[i][0];
        out[sb + (size_t)(2*i + 1) * PLANE_] = acc[i][1];
    }
}

// =================== Fallback (ws too small): fused + atomics ===============
__global__ __launch_bounds__(256, 5)
void llr_fused(const float* __restrict__ x, float* __restrict__ out) {
    __shared__ __align__(16) float Gl[4][4][320];
    const int warp = threadIdx.x >> 6;
    const int lane = threadIdx.x & 63;
    const int wid  = blockIdx.x * 4 + warp;
    if (wid >= NWAVE_) return;

    gram_jacobi_phi(x, wid, warp, lane, Gl);

    const int pr = lane >> 3, pc = lane & 7;
    for (int s = 0; s < 4; ++s) {
        const int id = wid*4 + s;
        const int n = id / NBB_, rem = id % NBB_;
        const int bi = rem / NB_, bj = rem % NB_;
        const int base = n*(A_*PLANE_) + (bi*4+pr)*W_ + (bj*4+pc);
        float mr[16];
        #pragma unroll
        for (int a = 0; a < 16; ++a) mr[a] = x[base + a*PLANE_];
        float o[16];
        #pragma unroll
        for (int a = 0; a < 16; ++a) o[a] = 0.f;
        #pragma unroll
        for (int k = 0; k < 16; ++k) {
            const float mk = mr[k];
            const float4 f0 = *(const float4*)&Gl[warp][s][k*20 + 0];
            const float4 f1 = *(const float4*)&Gl[warp][s][k*20 + 4];
            const float4 f2 = *(const float4*)&Gl[warp][s][k*20 + 8];
            const float4 f3 = *(const float4*)&Gl[warp][s][k*20 + 12];
            o[0]+=mk*f0.x;  o[1]+=mk*f0.y;  o[2]+=mk*f0.z;  o[3]+=mk*f0.w;
            o[4]+=mk*f1.x;  o[5]+=mk*f1.y;  o[6]+=mk*f1.z;  o[7]+=mk*f1.w;
            o[8]+=mk*f2.x;  o[9]+=mk*f2.y;  o[10]+=mk*f2.z; o[11]+=mk*f2.w;
            o[12]+=mk*f3.x; o[13]+=mk*f3.y; o[14]+=mk*f3.z; o[15]+=mk*f3.w;
        }
        #pragma unroll
        for (int a = 0; a < 16; ++a)
            unsafeAtomicAdd(&out[base + a*PLANE_], o[a]);
    }
}

__global__ __launch_bounds__(256)
void llr_div(float* __restrict__ out, const float* __restrict__ bw) {
    const int i = (blockIdx.x * 256 + threadIdx.x) * 4;
    float4 o = *(float4*)&out[i];
    const float4 bv = *(const float4*)&bw[i % PLANE_];
    o.x /= bv.x; o.y /= bv.y; o.z /= bv.z; o.w /= bv.w;
    *(float4*)&out[i] = o;
}

extern "C" void kernel_launch(void* const* d_in, const int* in_sizes, int n_in,
                              void* d_out, int out_size, void* d_ws, size_t ws_size,
                              hipStream_t stream) {
    (void)in_sizes; (void)n_in;
    const float* x  = (const float*)d_in[0];
    const float* bw = (const float*)d_in[1];
    float* out = (float*)d_out;

    if (ws_size >= PHI_BYTES_) {
        unsigned* phiG = (unsigned*)d_ws;
        hipLaunchKernelGGL(llr_phi,  dim3((NWAVE_ + 3) / 4), dim3(256), 0, stream, x, phiG);
        hipLaunchKernelGGL(llr_out2, dim3(4 * 48 * 12),      dim3(256), 0, stream, x, phiG, out);
    } else {
        hipMemsetAsync(out, 0, (size_t)out_size * sizeof(float), stream);
        hipLaunchKernelGGL(llr_fused, dim3((NWAVE_ + 3) / 4), dim3(256), 0, stream, x, out);
        hipLaunchKernelGGL(llr_div, dim3((N_*A_*PLANE_) / (256*4)), dim3(256), 0, stream, out, bw);
    }
}